// Round 9
// baseline (2208.296 us; speedup 1.0000x reference)
//
#include <hip/hip_runtime.h>
#include <cstddef>
#include <cstdint>

#define BATCH 32
#define CCH   512
#define OCH   1024
#define HW    3136
#define WDIM  56
#define NKT   16           // 512 / BK, BK=32

typedef __attribute__((ext_vector_type(8))) short short8v;  // 8 bf16
typedef __attribute__((ext_vector_type(4))) float f32x4;

// pair of fp32 -> packed bf16 hi-word + lo-word (R1-proven numerics).
static __device__ __forceinline__ void cvt2(float x0, float x1,
                                            unsigned& hw, unsigned& lw) {
    unsigned u0 = __float_as_uint(x0), u1 = __float_as_uint(x1);
    hw = (u1 & 0xffff0000u) | (u0 >> 16);
    float l0 = x0 - __uint_as_float(u0 & 0xffff0000u);
    float l1 = x1 - __uint_as_float(u1 & 0xffff0000u);
    unsigned r0 = __float_as_uint(l0), r1 = __float_as_uint(l1);
    r0 = r0 + 0x7fffu + ((r0 >> 16) & 1u);
    r1 = r1 + 0x7fffu + ((r1 >> 16) & 1u);
    lw = (r1 & 0xffff0000u) | (r0 >> 16);
}

static __device__ __forceinline__ int physlot(int s, int row) {
    return (s ^ (row & 7) ^ ((row >> 3) & 7)) & 7;
}

#define GLD_LDS16(gsrc, ldst) \
    __builtin_amdgcn_global_load_lds( \
        (const __attribute__((address_space(1))) void*)(gsrc), \
        (__attribute__((address_space(3))) void*)(ldst), 16, 0, 0)

// ---------------------------------------------------------------------------
// K0: pre-convert weights into LDS-image layout (R3-proven).
// ---------------------------------------------------------------------------
__global__ __launch_bounds__(256) void preconv_w(
    const float* __restrict__ wp, unsigned char* __restrict__ wcvt)
{
    const int id = blockIdx.x * 256 + threadIdx.x;   // 16384 = 1024 o x 16 kt
    const int o = id >> 4, kt = id & 15;
    const float* p = wp + (size_t)o * CCH + kt * 32;
    unsigned char* dst = wcvt + (size_t)o * 2048 + kt * 128;
    float4 v[8];
#pragma unroll
    for (int r = 0; r < 8; ++r) v[r] = *(const float4*)(p + 4 * r);
#pragma unroll
    for (int oc = 0; oc < 4; ++oc) {
        unsigned h0, w0, h1, w1, h2, w2, h3, w3;
        cvt2(v[2*oc].x,   v[2*oc].y,   h0, w0);
        cvt2(v[2*oc].z,   v[2*oc].w,   h1, w1);
        cvt2(v[2*oc+1].x, v[2*oc+1].y, h2, w2);
        cvt2(v[2*oc+1].z, v[2*oc+1].w, h3, w3);
        *(uint4*)(dst + physlot(oc, o) * 16)     = make_uint4(h0, h1, h2, h3);
        *(uint4*)(dst + physlot(4 + oc, o) * 16) = make_uint4(w0, w1, w2, w3);
    }
}

// ---------------------------------------------------------------------------
// K1: MFMA GEMM, tile 256(o) x 128(n), BK=32, 256 threads = 4 waves (2x2 of
// 128x64). LDS 48KB -> 3 blocks/CU: barrier drains of one block overlap the
// MFMA phase of another (m114 mechanism). NATURAL grid order, bx fastest:
// per-XCD working set = ~8 input panels (2MB, streaming) + 1MB wcvt slice,
// fits the 4MB L2. (R4's failure was the swizzle's 4MB+ wcvt/XCD thrash,
// not the occupancy.)
// ---------------------------------------------------------------------------
template <bool PRE>
__global__ __launch_bounds__(256, 3) void gemm_mfma(
    const float* __restrict__ in,          // [B,512,3136]
    const float* __restrict__ wp,          // [1024,512] (fallback path)
    const unsigned char* __restrict__ wc,  // wcvt (fast path)
    const float* __restrict__ bp,          // [1024]
    float* __restrict__ gate,              // d_out
    float* __restrict__ scan)              // ws (+2MB on fast path)
{
    const int bx = blockIdx.x;   // n-tile, fastest -> XCD streams input
    const int ot = blockIdx.y;   // o-tile 0..3
    const int b  = blockIdx.z;   // batch

    const int t  = threadIdx.x;
    const int lane = t & 63;
    const int wid  = t >> 6;           // 0..3
    const int wm = wid >> 1;           // o-strip of 128
    const int wn = wid & 1;            // n-strip of 64
    const int l15 = lane & 15, lko = lane >> 4;

    __shared__ __align__(16) unsigned char lds[49152];   // A 32K | B 16K
    unsigned char* ldsB = lds + 32768;

    const int o0 = ot * 256;
    const int n0 = bx * 128;

    // B staging role: thread (q = n-quad, kg = k-group of 4)
    const int q  = t & 31;
    const int kg = t >> 5;             // 0..7
    const int maxq = ((HW - n0) >> 2) - 1;
    const int qc = q < maxq ? q : maxq;
    const float* inB = in + (size_t)b * (CCH * (size_t)HW) + n0 + 4 * qc;

    f32x4 acc[8][4] = {};

    float4 bc[4], bn[4];
    {   // B(0): 4 k-rows of this thread's k-group
        const float* p = inB + (size_t)(kg * 4) * HW;
#pragma unroll
        for (int r = 0; r < 4; ++r) bc[r] = *(const float4*)(p + (size_t)r * HW);
    }

#pragma unroll 1
    for (int kt = 0; kt < NKT; ++kt) {
        // ---- write B(kt) to LDS (16x b32 per thread) ----
        {
            const int oc = kg >> 1;            // k-octet
            const int wb = (kg & 1) * 2;       // word base within slot
            unsigned h0, l0, h1, l1;
#define BCOL(C, COMP) \
            { const int nl = 4 * q + C; \
              unsigned char* row = ldsB + nl * 128; \
              cvt2(bc[0].COMP, bc[1].COMP, h0, l0); \
              cvt2(bc[2].COMP, bc[3].COMP, h1, l1); \
              unsigned* ph = (unsigned*)(row + physlot(oc, nl) * 16); \
              unsigned* pl = (unsigned*)(row + physlot(4 + oc, nl) * 16); \
              ph[wb] = h0; ph[wb + 1] = h1; \
              pl[wb] = l0; pl[wb + 1] = l1; }
            BCOL(0, x) BCOL(1, y) BCOL(2, z) BCOL(3, w)
#undef BCOL
        }

        // ---- stage A(kt): 256 rows x 128B via gld_lds from wcvt ----
        if constexpr (PRE) {
            const unsigned char* srcb = wc + (size_t)o0 * 2048 + kt * 128;
            const int sub = (t & 7) * 16;
            const int rbase = t >> 3;
#pragma unroll
            for (int j = 0; j < 8; ++j) {
                const int row = j * 32 + rbase;
                void* dstu = lds + j * 4096 + wid * 1024;  // wave-uniform base
                GLD_LDS16(srcb + (size_t)row * 2048 + sub, dstu);
            }
        } else {
            const float* p = wp + (size_t)(o0 + t) * CCH + kt * 32;
            float4 av[8];
#pragma unroll
            for (int r = 0; r < 8; ++r) av[r] = *(const float4*)(p + 4 * r);
            unsigned char* rowa = lds + t * 128;
#pragma unroll
            for (int oc = 0; oc < 4; ++oc) {
                unsigned h0, w0, h1, w1, h2, w2, h3, w3;
                cvt2(av[2*oc].x,   av[2*oc].y,   h0, w0);
                cvt2(av[2*oc].z,   av[2*oc].w,   h1, w1);
                cvt2(av[2*oc+1].x, av[2*oc+1].y, h2, w2);
                cvt2(av[2*oc+1].z, av[2*oc+1].w, h3, w3);
                *(uint4*)(rowa + physlot(oc, t) * 16)     = make_uint4(h0, h1, h2, h3);
                *(uint4*)(rowa + physlot(4 + oc, t) * 16) = make_uint4(w0, w1, w2, w3);
            }
        }

        asm volatile("" ::: "memory");

        // ---- prefetch B(kt+1) into regs; counted vmcnt keeps it in flight ----
        if (kt + 1 < NKT) {
            const float* p = inB + (size_t)((kt + 1) * 32 + kg * 4) * HW;
#pragma unroll
            for (int r = 0; r < 4; ++r) bn[r] = *(const float4*)(p + (size_t)r * HW);
            if constexpr (PRE) asm volatile("s_waitcnt vmcnt(4)" ::: "memory");
        } else {
            if constexpr (PRE) asm volatile("s_waitcnt vmcnt(0)" ::: "memory");
        }
        asm volatile("s_waitcnt lgkmcnt(0)" ::: "memory");
        __builtin_amdgcn_s_barrier();
        asm volatile("" ::: "memory");

        // ---- fragments + MFMA ----
        short8v bfh[4], bfl[4];
#pragma unroll
        for (int g = 0; g < 4; ++g) {
            const int n = wn * 64 + g * 16 + l15;
            const unsigned char* rb = ldsB + n * 128;
            bfh[g] = *(const short8v*)(rb + physlot(lko, n) * 16);
            bfl[g] = *(const short8v*)(rb + physlot(4 + lko, n) * 16);
        }
#pragma unroll
        for (int fh = 0; fh < 2; ++fh) {
            short8v ah[4], al[4];
#pragma unroll
            for (int fi = 0; fi < 4; ++fi) {
                const int r = wm * 128 + (fh * 4 + fi) * 16 + l15;
                const unsigned char* ra = lds + r * 128;
                ah[fi] = *(const short8v*)(ra + physlot(lko, r) * 16);
                al[fi] = *(const short8v*)(ra + physlot(4 + lko, r) * 16);
            }
#pragma unroll
            for (int fi = 0; fi < 4; ++fi)
#pragma unroll
                for (int g = 0; g < 4; ++g) {
                    f32x4 c = acc[fh * 4 + fi][g];
                    c = __builtin_amdgcn_mfma_f32_16x16x32_bf16(ah[fi], bfh[g], c, 0, 0, 0);
                    c = __builtin_amdgcn_mfma_f32_16x16x32_bf16(al[fi], bfh[g], c, 0, 0, 0);
                    c = __builtin_amdgcn_mfma_f32_16x16x32_bf16(ah[fi], bfl[g], c, 0, 0, 0);
                    acc[fh * 4 + fi][g] = c;
                }
        }

        asm volatile("" ::: "memory");
        __builtin_amdgcn_s_barrier();
        asm volatile("" ::: "memory");

#pragma unroll
        for (int r = 0; r < 4; ++r) bc[r] = bn[r];
    }

    // ---- epilogue: bias + store (C: row = lko*4+rg, col = l15) ----
    float* dstb = (ot < 2) ? gate : scan;
    const int c0 = o0 & (CCH - 1);
#pragma unroll
    for (int f = 0; f < 8; ++f) {
        const int rowb = wm * 128 + f * 16 + lko * 4;
#pragma unroll
        for (int rg = 0; rg < 4; ++rg) {
            const int o = o0 + rowb + rg;
            const float bias = bp[o];
            float* drow = dstb + ((size_t)b * CCH + c0 + rowb + rg) * HW;
#pragma unroll
            for (int g = 0; g < 4; ++g) {
                const int n = n0 + wn * 64 + g * 16 + l15;
                if (n < HW) drow[n] = acc[f][g][rg] + bias;
            }
        }
    }
}

// ---------------------------------------------------------------------------
// K2: per-(b,c) 2D discounted scan + fused epilogue (R0-proven).
// ---------------------------------------------------------------------------
__global__ __launch_bounds__(64) void scan_fuse(
    const float* __restrict__ in,
    const float* __restrict__ scanb,
    const float* __restrict__ disc,
    const float* __restrict__ gamma,
    float* gate_out)
{
    const int idx = blockIdx.x;
    const int c = idx & (CCH - 1);
    const size_t base = (size_t)idx * HW;
    const float d = disc[c];
    const float g = gamma[0];
    const int lane = threadIdx.x;

    __shared__ float L[WDIM * 57];

    if (lane < WDIM) {
        const int w = lane;
        float acc = 0.f;
#pragma unroll 4
        for (int h = 0; h < WDIM; h++) {
            acc = fmaf(d, acc, scanb[base + h * WDIM + w]);
            L[h * 57 + w] = acc;
        }
    }
    __syncthreads();
    if (lane < WDIM) {
        const int h = lane;
        float acc = 0.f;
#pragma unroll 4
        for (int w = 0; w < WDIM; w++) {
            acc = fmaf(d, acc, L[h * 57 + w]);
            L[h * 57 + w] = acc;
        }
    }
    __syncthreads();
    if (lane < WDIM) {
        const int w = lane;
#pragma unroll 4
        for (int h = 0; h < WDIM; h++) {
            const size_t off = base + h * WDIM + w;
            const float xc = L[h * 57 + w];
            const float sg = 1.f / (1.f + __expf(-xc));
            const float val = fmaf(g * gate_out[off], sg, in[off]);
            gate_out[off] = val;
        }
    }
}

extern "C" void kernel_launch(void* const* d_in, const int* in_sizes, int n_in,
                              void* d_out, int out_size, void* d_ws, size_t ws_size,
                              hipStream_t stream) {
    const float* in = (const float*)d_in[0];
    const float* wp = (const float*)d_in[1];
    const float* bp = (const float*)d_in[2];
    const float* dc = (const float*)d_in[3];
    const float* gm = (const float*)d_in[4];
    float* out = (float*)d_out;

    const size_t scan_bytes = (size_t)BATCH * CCH * HW * 4;   // 205.5 MB
    const size_t wcvt_bytes = (size_t)OCH * CCH * 4;          // 2 MB
    const bool pre = ws_size >= scan_bytes + wcvt_bytes;

    unsigned char* wcvt = (unsigned char*)d_ws;
    float* scanp = (float*)((unsigned char*)d_ws + (pre ? wcvt_bytes : 0));

    dim3 g1(25, 4, BATCH);   // bx fastest: natural, streams input per XCD
    if (pre) {
        preconv_w<<<64, 256, 0, stream>>>(wp, wcvt);
        gemm_mfma<true><<<g1, 256, 0, stream>>>(in, wp, wcvt, bp, out, scanp);
    } else {
        gemm_mfma<false><<<g1, 256, 0, stream>>>(in, wp, wcvt, bp, out, scanp);
    }

    scan_fuse<<<BATCH * CCH, 64, 0, stream>>>(in, scanp, dc, gm, out);
}

// Round 10
// 540.600 us; speedup vs baseline: 4.0849x; 4.0849x over previous
//
#include <hip/hip_runtime.h>
#include <cstddef>
#include <cstdint>

#define BATCH 32
#define CCH   512
#define OCH   1024
#define HW    3136
#define WDIM  56
#define NKT   16           // 512 / BK, BK=32

typedef __attribute__((ext_vector_type(8))) short short8v;  // 8 bf16
typedef __attribute__((ext_vector_type(4))) float f32x4;

// RNE round two fp32 to bf16, packed (x0 -> lo16, x1 -> hi16).
static __device__ __forceinline__ unsigned rne2(float x0, float x1) {
    unsigned u0 = __float_as_uint(x0), u1 = __float_as_uint(x1);
    u0 = u0 + 0x7fffu + ((u0 >> 16) & 1u);
    u1 = u1 + 0x7fffu + ((u1 >> 16) & 1u);
    return (u0 >> 16) | (u1 & 0xffff0000u);
}

// 4 slots of 16B per 64-B row; XOR swizzle -> 2-way max on frag reads (free).
static __device__ __forceinline__ int physlot4(int s, int row) {
    return (s ^ (row & 3) ^ ((row >> 2) & 3)) & 3;
}

#define GLD_LDS16(gsrc, ldst) \
    __builtin_amdgcn_global_load_lds( \
        (const __attribute__((address_space(1))) void*)(gsrc), \
        (__attribute__((address_space(3))) void*)(ldst), 16, 0, 0)

#define MFMA16(a, bb, c) __builtin_amdgcn_mfma_f32_16x16x32_bf16((a), (bb), (c), 0, 0, 0)

// ---------------------------------------------------------------------------
// K0: pre-convert weights (RNE bf16) into the exact LDS image:
// wcvt[o][kt] = 64 B: 4 slots of 8 bf16 (k-octets), slot s at physlot4(s,o).
// Total 1 MB -> L2-resident.
// ---------------------------------------------------------------------------
__global__ __launch_bounds__(256) void preconv_w(
    const float* __restrict__ wp, unsigned char* __restrict__ wcvt)
{
    const int id = blockIdx.x * 256 + threadIdx.x;   // 16384 = 1024 o x 16 kt
    const int o = id >> 4, kt = id & 15;
    const float* p = wp + (size_t)o * CCH + kt * 32;
    unsigned char* dst = wcvt + (size_t)o * 1024 + kt * 64;
    float4 v[8];
#pragma unroll
    for (int r = 0; r < 8; ++r) v[r] = *(const float4*)(p + 4 * r);
#pragma unroll
    for (int oc = 0; oc < 4; ++oc) {
        uint4 w;
        w.x = rne2(v[2*oc].x,   v[2*oc].y);
        w.y = rne2(v[2*oc].z,   v[2*oc].w);
        w.z = rne2(v[2*oc+1].x, v[2*oc+1].y);
        w.w = rne2(v[2*oc+1].z, v[2*oc+1].w);
        *(uint4*)(dst + physlot4(oc, o) * 16) = w;
    }
}

// ---------------------------------------------------------------------------
// K1: single-bf16 MFMA GEMM, tile 512(o) x 128(n), BK=32, 512 thr = 8 waves
// (4x2 of 128x64). LDS 80 KB (A 32Kx2 dbuf + B 8Kx2) -> 2 blocks/CU for
// cross-block overlap without the R9 working-set explosion.
// Per kt: {writeB(kt+1), stageA(kt+1) DMA, loadB(kt+2)} issued first, then
// frag reads + 32 MFMA, single barrier with vmcnt(2) (B regs stay in flight).
// ---------------------------------------------------------------------------
template <bool PRE>
__global__ __launch_bounds__(512, 2) void gemm_bf16(
    const float* __restrict__ in,          // [B,512,3136]
    const float* __restrict__ wp,          // [1024,512] (fallback path)
    const unsigned char* __restrict__ wc,  // wcvt (fast path)
    const float* __restrict__ bp,          // [1024]
    float* __restrict__ gate,              // d_out
    float* __restrict__ scan)              // ws (+1MB on fast path)
{
    const int bx = blockIdx.x;   // 0..24 n-tiles of 128 (last is half)
    const int by = blockIdx.y;   // 0: gate, 1: scan
    const int b  = blockIdx.z;
    const int t  = threadIdx.x;
    const int lane = t & 63;
    const int wid  = t >> 6;           // 0..7
    const int wm = wid >> 1;           // o-strip of 128
    const int wn = wid & 1;            // n-strip of 64
    const int l15 = lane & 15, lko = lane >> 4;

    __shared__ __align__(16) unsigned char lds[81920];
    unsigned char* const A0 = lds;             // 32 KB (512 rows x 64 B)
    unsigned char* const A1 = lds + 32768;
    unsigned char* const B0 = lds + 65536;     // 8 KB (128 rows x 64 B)
    unsigned char* const B1 = lds + 73728;

    const int o0 = by * 512;
    const int n0 = bx * 128;

    // B staging role: thread (q = n-quad 0..31, kb = k-pair 0..15)
    const int q  = t >> 4;
    const int kb = t & 15;
    const int maxq = ((HW - n0) >> 2) - 1;
    const int qc = q < maxq ? q : maxq;
    const float* inB = in + (size_t)b * (CCH * (size_t)HW) + n0 + 4 * qc;

    f32x4 acc[8][4] = {};
    float4 bcA, bcB;   // two k-rows (k = 2kb, 2kb+1) x 4 cols

    auto loadB = [&](int kt) {
        const float* p = inB + (size_t)(kt * 32 + kb * 2) * HW;
        bcA = *(const float4*)p;
        bcB = *(const float4*)(p + HW);
    };

    auto writeB = [&](unsigned char* dB) {
        const int s  = kb >> 2;          // k-octet
        const int sb = (kb & 3) * 4;     // byte within slot
#define BCOL(C, COMP) \
        { const int nl = 4 * q + C; \
          *(unsigned*)(dB + nl * 64 + physlot4(s, nl) * 16 + sb) = \
              rne2(bcA.COMP, bcB.COMP); }
        BCOL(0, x) BCOL(1, y) BCOL(2, z) BCOL(3, w)
#undef BCOL
    };

    auto stageA = [&](int kt, unsigned char* An) {
        if constexpr (PRE) {
            // 32 KB = 4 rounds x (512 threads x 16 B), LDS dest linear.
            const unsigned char* srcb =
                wc + (size_t)(o0 + (t >> 2)) * 1024 + kt * 64 + (t & 3) * 16;
#pragma unroll
            for (int j = 0; j < 4; ++j) {
                void* dstu = An + j * 8192 + wid * 1024;   // wave-uniform base
                GLD_LDS16(srcb + (size_t)(j * 128) * 1024, dstu);
            }
        } else {
            // fallback: convert weights in-kernel (one row of 32 k per thread)
            const float* p = wp + (size_t)(o0 + t) * CCH + kt * 32;
            float4 av[8];
#pragma unroll
            for (int r = 0; r < 8; ++r) av[r] = *(const float4*)(p + 4 * r);
            unsigned char* rowa = An + t * 64;
#pragma unroll
            for (int oc = 0; oc < 4; ++oc) {
                uint4 w;
                w.x = rne2(av[2*oc].x,   av[2*oc].y);
                w.y = rne2(av[2*oc].z,   av[2*oc].w);
                w.z = rne2(av[2*oc+1].x, av[2*oc+1].y);
                w.w = rne2(av[2*oc+1].z, av[2*oc+1].w);
                *(uint4*)(rowa + physlot4(oc, t) * 16) = w;
            }
        }
    };

    auto body = [&](int kt, unsigned char* Ac, unsigned char* Bc,
                    unsigned char* An, unsigned char* Bn) {
        const bool notlast = (kt + 1 < NKT);
        // ---- phase 1: issue next-tile staging ----
        if (notlast) {
            writeB(Bn);                       // regs hold B(kt+1)
            stageA(kt + 1, An);               // 4 gld_lds in flight
            if (kt + 2 < NKT) loadB(kt + 2);  // 2 loads fly past the barrier
        }
        asm volatile("" ::: "memory");

        // ---- phase 2: fragments + MFMA ----
        short8v bf[4];
#pragma unroll
        for (int g = 0; g < 4; ++g) {
            const int n = wn * 64 + g * 16 + l15;
            bf[g] = *(const short8v*)(Bc + n * 64 + physlot4(lko, n) * 16);
        }
        short8v af[8];
#pragma unroll
        for (int fi = 0; fi < 8; ++fi) {
            const int r = wm * 128 + fi * 16 + l15;
            af[fi] = *(const short8v*)(Ac + r * 64 + physlot4(lko, r) * 16);
        }
        __builtin_amdgcn_s_setprio(1);
#pragma unroll
        for (int fi = 0; fi < 8; ++fi)
#pragma unroll
            for (int g = 0; g < 4; ++g)
                acc[fi][g] = MFMA16(af[fi], bf[g], acc[fi][g]);
        __builtin_amdgcn_s_setprio(0);

        // ---- single barrier; counted vmcnt keeps B regs in flight ----
        if (notlast) {
            if constexpr (PRE) {
                if (kt + 2 < NKT) asm volatile("s_waitcnt vmcnt(2)" ::: "memory");
                else              asm volatile("s_waitcnt vmcnt(0)" ::: "memory");
            }
            asm volatile("s_waitcnt lgkmcnt(0)" ::: "memory");
            __builtin_amdgcn_s_barrier();
            asm volatile("" ::: "memory");
        }
    };

    // ---- prologue: tile 0 -> buf0, B(1) -> regs ----
    loadB(0);
    writeB(B0);
    stageA(0, A0);
    loadB(1);
    if constexpr (PRE) asm volatile("s_waitcnt vmcnt(2)" ::: "memory");
    asm volatile("s_waitcnt lgkmcnt(0)" ::: "memory");
    __builtin_amdgcn_s_barrier();
    asm volatile("" ::: "memory");

#pragma unroll 1
    for (int kt2 = 0; kt2 < NKT; kt2 += 2) {
        body(kt2,     A0, B0, A1, B1);
        body(kt2 + 1, A1, B1, A0, B0);
    }

    // ---- epilogue: bias + store (C: row = lko*4+rg, col = l15) ----
    float* dstb = (by == 0) ? gate : scan;
#pragma unroll
    for (int f = 0; f < 8; ++f) {
        const int rowb = wm * 128 + f * 16 + lko * 4;
#pragma unroll
        for (int rg = 0; rg < 4; ++rg) {
            const int o = o0 + rowb + rg;
            const float bias = bp[o];
            float* drow = dstb + ((size_t)b * CCH + (o & (CCH - 1))) * HW;
#pragma unroll
            for (int g = 0; g < 4; ++g) {
                const int n = n0 + wn * 64 + g * 16 + l15;
                if (n < HW) drow[n] = acc[f][g][rg] + bias;
            }
        }
    }
}

// ---------------------------------------------------------------------------
// K2: per-(b,c) 2D discounted scan + fused epilogue (R0-proven).
// ---------------------------------------------------------------------------
__global__ __launch_bounds__(64) void scan_fuse(
    const float* __restrict__ in,
    const float* __restrict__ scanb,
    const float* __restrict__ disc,
    const float* __restrict__ gamma,
    float* gate_out)
{
    const int idx = blockIdx.x;
    const int c = idx & (CCH - 1);
    const size_t base = (size_t)idx * HW;
    const float d = disc[c];
    const float g = gamma[0];
    const int lane = threadIdx.x;

    __shared__ float L[WDIM * 57];

    if (lane < WDIM) {
        const int w = lane;
        float acc = 0.f;
#pragma unroll 4
        for (int h = 0; h < WDIM; h++) {
            acc = fmaf(d, acc, scanb[base + h * WDIM + w]);
            L[h * 57 + w] = acc;
        }
    }
    __syncthreads();
    if (lane < WDIM) {
        const int h = lane;
        float acc = 0.f;
#pragma unroll 4
        for (int w = 0; w < WDIM; w++) {
            acc = fmaf(d, acc, L[h * 57 + w]);
            L[h * 57 + w] = acc;
        }
    }
    __syncthreads();
    if (lane < WDIM) {
        const int w = lane;
#pragma unroll 4
        for (int h = 0; h < WDIM; h++) {
            const size_t off = base + h * WDIM + w;
            const float xc = L[h * 57 + w];
            const float sg = 1.f / (1.f + __expf(-xc));
            const float val = fmaf(g * gate_out[off], sg, in[off]);
            gate_out[off] = val;
        }
    }
}

extern "C" void kernel_launch(void* const* d_in, const int* in_sizes, int n_in,
                              void* d_out, int out_size, void* d_ws, size_t ws_size,
                              hipStream_t stream) {
    const float* in = (const float*)d_in[0];
    const float* wp = (const float*)d_in[1];
    const float* bp = (const float*)d_in[2];
    const float* dc = (const float*)d_in[3];
    const float* gm = (const float*)d_in[4];
    float* out = (float*)d_out;

    const size_t scan_bytes = (size_t)BATCH * CCH * HW * 4;   // 205.5 MB
    const size_t wcvt_bytes = (size_t)OCH * CCH * 2;          // 1 MB
    const bool pre = ws_size >= scan_bytes + wcvt_bytes;

    unsigned char* wcvt = (unsigned char*)d_ws;
    float* scanp = (float*)((unsigned char*)d_ws + (pre ? wcvt_bytes : 0));

    dim3 g1(25, 2, BATCH);
    if (pre) {
        preconv_w<<<64, 256, 0, stream>>>(wp, wcvt);
        gemm_bf16<true><<<g1, 512, 0, stream>>>(in, wp, wcvt, bp, out, scanp);
    } else {
        gemm_bf16<false><<<g1, 512, 0, stream>>>(in, wp, wcvt, bp, out, scanp);
    }

    scan_fuse<<<BATCH * CCH, 64, 0, stream>>>(in, scanp, dc, gm, out);
}

// Round 11
// 527.711 us; speedup vs baseline: 4.1847x; 1.0244x over previous
//
#include <hip/hip_runtime.h>
#include <cstddef>
#include <cstdint>

#define BATCH 32
#define CCH   512
#define OCH   1024
#define HW    3136
#define WDIM  56
#define NKT   16           // 512 / BK, BK=32

typedef __attribute__((ext_vector_type(8))) short short8v;  // 8 bf16
typedef __attribute__((ext_vector_type(4))) float f32x4;

// RNE round two fp32 to bf16, packed (x0 -> lo16, x1 -> hi16).
static __device__ __forceinline__ unsigned rne2(float x0, float x1) {
    unsigned u0 = __float_as_uint(x0), u1 = __float_as_uint(x1);
    u0 = u0 + 0x7fffu + ((u0 >> 16) & 1u);
    u1 = u1 + 0x7fffu + ((u1 >> 16) & 1u);
    return (u0 >> 16) | (u1 & 0xffff0000u);
}

// 4 slots of 16B per 64-B row; XOR swizzle -> ~2-way max on frag reads.
static __device__ __forceinline__ int physlot4(int s, int row) {
    return (s ^ (row & 3) ^ ((row >> 2) & 3)) & 3;
}

#define GLD_LDS16(gsrc, ldst) \
    __builtin_amdgcn_global_load_lds( \
        (const __attribute__((address_space(1))) void*)(gsrc), \
        (__attribute__((address_space(3))) void*)(ldst), 16, 0, 0)

#define MFMA16(a, bb, c) __builtin_amdgcn_mfma_f32_16x16x32_bf16((a), (bb), (c), 0, 0, 0)

// ---------------------------------------------------------------------------
// K0a: pre-convert weights (RNE bf16) into the LDS image (R10-proven):
// wcvt[o][kt] = 64 B: 4 slots of 8 bf16 k-octets, slot s at physlot4(s,o).
// ---------------------------------------------------------------------------
__global__ __launch_bounds__(256) void preconv_w(
    const float* __restrict__ wp, unsigned char* __restrict__ wcvt)
{
    const int id = blockIdx.x * 256 + threadIdx.x;   // 16384 = 1024 o x 16 kt
    const int o = id >> 4, kt = id & 15;
    const float* p = wp + (size_t)o * CCH + kt * 32;
    unsigned char* dst = wcvt + (size_t)o * 1024 + kt * 64;
    float4 v[8];
#pragma unroll
    for (int r = 0; r < 8; ++r) v[r] = *(const float4*)(p + 4 * r);
#pragma unroll
    for (int oc = 0; oc < 4; ++oc) {
        uint4 w;
        w.x = rne2(v[2*oc].x,   v[2*oc].y);
        w.y = rne2(v[2*oc].z,   v[2*oc].w);
        w.z = rne2(v[2*oc+1].x, v[2*oc+1].y);
        w.w = rne2(v[2*oc+1].z, v[2*oc+1].w);
        *(uint4*)(dst + physlot4(oc, o) * 16) = w;
    }
}

// ---------------------------------------------------------------------------
// K0b: convert+transpose input to bin[b][kt][n][32k] bf16 chunks (64 B per
// (b,kt,n)): exactly the GEMM's B LDS image order, so B staging is a single
// coalesced 16 B reg load + 1 ds_write. 103 MB total (L3-resident).
// ---------------------------------------------------------------------------
__global__ __launch_bounds__(256) void conv_in(
    const float* __restrict__ in, unsigned char* __restrict__ bin)
{
    const int nt = blockIdx.x;      // 0..48 (64-n tiles)
    const int kt = blockIdx.y;      // 0..15
    const int b  = blockIdx.z;
    const int t  = threadIdx.x;
    __shared__ float sm[32 * 65];

    const int n0 = nt * 64;
    const int row = t >> 3;             // 0..31 (k within tile)
    const int c8  = (t & 7) * 8;        // 0..56
    const float* src = in + ((size_t)b * CCH + kt * 32 + row) * HW + n0 + c8;
    float4 v0 = *(const float4*)src;
    float4 v1 = *(const float4*)(src + 4);
    float* sr = sm + row * 65 + c8;
    sr[0] = v0.x; sr[1] = v0.y; sr[2] = v0.z; sr[3] = v0.w;
    sr[4] = v1.x; sr[5] = v1.y; sr[6] = v1.z; sr[7] = v1.w;
    __syncthreads();

    const int n = t >> 2, sub = t & 3;  // n 0..63, k-octet sub
    const int k0 = sub * 8;
    uint4 w;
    w.x = rne2(sm[(k0 + 0) * 65 + n], sm[(k0 + 1) * 65 + n]);
    w.y = rne2(sm[(k0 + 2) * 65 + n], sm[(k0 + 3) * 65 + n]);
    w.z = rne2(sm[(k0 + 4) * 65 + n], sm[(k0 + 5) * 65 + n]);
    w.w = rne2(sm[(k0 + 6) * 65 + n], sm[(k0 + 7) * 65 + n]);
    *(uint4*)(bin + (((size_t)b * 16 + kt) * HW + n0 + n) * 64 + sub * 16) = w;
}

// ---------------------------------------------------------------------------
// K1: single-bf16 MFMA GEMM, tile 512(o) x 128(n), BK=32, 512 thr = 8 waves
// (4x2 of 128x64), LDS 80 KB dbuf (A 32Kx2 + B 8Kx2) -> 2 blocks/CU.
// MODE 2: A via gld_lds from wcvt; B via 16B reg load from bin + 1 ds_write.
// MODE 1: A via gld_lds; B fp32 loads + in-kernel cvt (R10-proven).
// MODE 0: both converted in-kernel (no ws needed beyond scan).
// ---------------------------------------------------------------------------
template <int MODE>
__global__ __launch_bounds__(512, 2) void gemm_bf16(
    const float* __restrict__ in,          // [B,512,3136]
    const float* __restrict__ wp,          // [1024,512]
    const unsigned char* __restrict__ wc,  // wcvt
    const unsigned char* __restrict__ bin, // bin (MODE 2)
    const float* __restrict__ bp,          // [1024]
    float* __restrict__ gate,              // d_out
    float* __restrict__ scan)              // ws scan region
{
    const int bx = blockIdx.x;   // 0..24 n-tiles of 128 (last is half)
    const int by = blockIdx.y;   // 0: gate, 1: scan
    const int b  = blockIdx.z;
    const int t  = threadIdx.x;
    const int lane = t & 63;
    const int wid  = t >> 6;           // 0..7
    const int wm = wid >> 1;           // o-strip of 128
    const int wn = wid & 1;            // n-strip of 64
    const int l15 = lane & 15, lko = lane >> 4;

    __shared__ __align__(16) unsigned char lds[81920];
    unsigned char* const A0 = lds;             // 32 KB (512 rows x 64 B)
    unsigned char* const A1 = lds + 32768;
    unsigned char* const B0 = lds + 65536;     // 8 KB (128 rows x 64 B)
    unsigned char* const B1 = lds + 73728;

    const int o0 = by * 512;
    const int n0 = bx * 128;

    // ---- MODE 0/1 B staging role ----
    const int q  = t >> 4;
    const int kb = t & 15;
    const int maxq = ((HW - n0) >> 2) - 1;
    const int qc = q < maxq ? q : maxq;
    const float* inB = in + (size_t)b * (CCH * (size_t)HW) + n0 + 4 * qc;
    float4 bcA, bcB;

    // ---- MODE 2 B staging: contiguous 8 KB per (b,kt,n-tile) ----
    const unsigned char* binB = bin + ((size_t)b * 16 * HW + n0) * 64 + t * 16;
    uint4 breg;

    f32x4 acc[8][4] = {};

    auto loadB = [&](int kt) {
        const float* p = inB + (size_t)(kt * 32 + kb * 2) * HW;
        bcA = *(const float4*)p;
        bcB = *(const float4*)(p + HW);
    };
    auto writeB = [&](unsigned char* dB) {
        const int s  = kb >> 2;
        const int sb = (kb & 3) * 4;
#define BCOL(C, COMP) \
        { const int nl = 4 * q + C; \
          *(unsigned*)(dB + nl * 64 + physlot4(s, nl) * 16 + sb) = \
              rne2(bcA.COMP, bcB.COMP); }
        BCOL(0, x) BCOL(1, y) BCOL(2, z) BCOL(3, w)
#undef BCOL
    };

    auto loadB2 = [&](int kt) {
        breg = *(const uint4*)(binB + (size_t)kt * (HW * 64));
    };
    auto writeB2 = [&](unsigned char* dB) {
        const int nl = t >> 2, s = t & 3;
        *(uint4*)(dB + nl * 64 + physlot4(s, nl) * 16) = breg;
    };

    auto stageA = [&](int kt, unsigned char* An) {
        if constexpr (MODE >= 1) {
            const unsigned char* srcb =
                wc + (size_t)(o0 + (t >> 2)) * 1024 + kt * 64 + (t & 3) * 16;
#pragma unroll
            for (int j = 0; j < 4; ++j) {
                void* dstu = An + j * 8192 + wid * 1024;   // wave-uniform base
                GLD_LDS16(srcb + (size_t)(j * 128) * 1024, dstu);
            }
        } else {
            const float* p = wp + (size_t)(o0 + t) * CCH + kt * 32;
            float4 av[8];
#pragma unroll
            for (int r = 0; r < 8; ++r) av[r] = *(const float4*)(p + 4 * r);
            unsigned char* rowa = An + t * 64;
#pragma unroll
            for (int oc = 0; oc < 4; ++oc) {
                uint4 w;
                w.x = rne2(av[2*oc].x,   av[2*oc].y);
                w.y = rne2(av[2*oc].z,   av[2*oc].w);
                w.z = rne2(av[2*oc+1].x, av[2*oc+1].y);
                w.w = rne2(av[2*oc+1].z, av[2*oc+1].w);
                *(uint4*)(rowa + physlot4(oc, t) * 16) = w;
            }
        }
    };

    auto body = [&](int kt, unsigned char* Ac, unsigned char* Bc,
                    unsigned char* An, unsigned char* Bn) {
        const bool notlast = (kt + 1 < NKT);
        // ---- phase 1: issue next-tile staging ----
        if (notlast) {
            if constexpr (MODE == 2) {
                writeB2(Bn);                       // breg holds B(kt+1)
                stageA(kt + 1, An);                // 4 gld_lds in flight
                if (kt + 2 < NKT) loadB2(kt + 2);  // 1 load flies past barrier
            } else {
                writeB(Bn);
                stageA(kt + 1, An);
                if (kt + 2 < NKT) loadB(kt + 2);
            }
        }
        asm volatile("" ::: "memory");

        // ---- phase 2: fragments + MFMA ----
        short8v bf[4];
#pragma unroll
        for (int g = 0; g < 4; ++g) {
            const int n = wn * 64 + g * 16 + l15;
            bf[g] = *(const short8v*)(Bc + n * 64 + physlot4(lko, n) * 16);
        }
        short8v af[8];
#pragma unroll
        for (int fi = 0; fi < 8; ++fi) {
            const int r = wm * 128 + fi * 16 + l15;
            af[fi] = *(const short8v*)(Ac + r * 64 + physlot4(lko, r) * 16);
        }
        __builtin_amdgcn_s_setprio(1);
#pragma unroll
        for (int fi = 0; fi < 8; ++fi)
#pragma unroll
            for (int g = 0; g < 4; ++g)
                acc[fi][g] = MFMA16(af[fi], bf[g], acc[fi][g]);
        __builtin_amdgcn_s_setprio(0);

        // ---- single barrier; counted vmcnt keeps next B load in flight ----
        if (notlast) {
            if constexpr (MODE == 2) {
                if (kt + 2 < NKT) asm volatile("s_waitcnt vmcnt(1)" ::: "memory");
                else              asm volatile("s_waitcnt vmcnt(0)" ::: "memory");
            } else if constexpr (MODE == 1) {
                if (kt + 2 < NKT) asm volatile("s_waitcnt vmcnt(2)" ::: "memory");
                else              asm volatile("s_waitcnt vmcnt(0)" ::: "memory");
            }
            asm volatile("s_waitcnt lgkmcnt(0)" ::: "memory");
            __builtin_amdgcn_s_barrier();
            asm volatile("" ::: "memory");
        }
    };

    // ---- prologue: tile 0 -> buf0, B(1) -> regs ----
    if constexpr (MODE == 2) {
        loadB2(0);
        writeB2(B0);
        stageA(0, A0);
        loadB2(1);
        asm volatile("s_waitcnt vmcnt(1)" ::: "memory");
    } else {
        loadB(0);
        writeB(B0);
        stageA(0, A0);
        loadB(1);
        if constexpr (MODE == 1) asm volatile("s_waitcnt vmcnt(2)" ::: "memory");
    }
    asm volatile("s_waitcnt lgkmcnt(0)" ::: "memory");
    __builtin_amdgcn_s_barrier();
    asm volatile("" ::: "memory");

#pragma unroll 1
    for (int kt2 = 0; kt2 < NKT; kt2 += 2) {
        body(kt2,     A0, B0, A1, B1);
        body(kt2 + 1, A1, B1, A0, B0);
    }

    // ---- epilogue: bias + store (C: row = lko*4+rg, col = l15) ----
    float* dstb = (by == 0) ? gate : scan;
#pragma unroll
    for (int f = 0; f < 8; ++f) {
        const int rowb = wm * 128 + f * 16 + lko * 4;
#pragma unroll
        for (int rg = 0; rg < 4; ++rg) {
            const int o = o0 + rowb + rg;
            const float bias = bp[o];
            float* drow = dstb + ((size_t)b * CCH + (o & (CCH - 1))) * HW;
#pragma unroll
            for (int g = 0; g < 4; ++g) {
                const int n = n0 + wn * 64 + g * 16 + l15;
                if (n < HW) drow[n] = acc[f][g][rg] + bias;
            }
        }
    }
}

// ---------------------------------------------------------------------------
// K2: per-(b,c) 2D discounted scan + fused epilogue (R0-proven).
// ---------------------------------------------------------------------------
__global__ __launch_bounds__(64) void scan_fuse(
    const float* __restrict__ in,
    const float* __restrict__ scanb,
    const float* __restrict__ disc,
    const float* __restrict__ gamma,
    float* gate_out)
{
    const int idx = blockIdx.x;
    const int c = idx & (CCH - 1);
    const size_t base = (size_t)idx * HW;
    const float d = disc[c];
    const float g = gamma[0];
    const int lane = threadIdx.x;

    __shared__ float L[WDIM * 57];

    if (lane < WDIM) {
        const int w = lane;
        float acc = 0.f;
#pragma unroll 4
        for (int h = 0; h < WDIM; h++) {
            acc = fmaf(d, acc, scanb[base + h * WDIM + w]);
            L[h * 57 + w] = acc;
        }
    }
    __syncthreads();
    if (lane < WDIM) {
        const int h = lane;
        float acc = 0.f;
#pragma unroll 4
        for (int w = 0; w < WDIM; w++) {
            acc = fmaf(d, acc, L[h * 57 + w]);
            L[h * 57 + w] = acc;
        }
    }
    __syncthreads();
    if (lane < WDIM) {
        const int w = lane;
#pragma unroll 4
        for (int h = 0; h < WDIM; h++) {
            const size_t off = base + h * WDIM + w;
            const float xc = L[h * 57 + w];
            const float sg = 1.f / (1.f + __expf(-xc));
            const float val = fmaf(g * gate_out[off], sg, in[off]);
            gate_out[off] = val;
        }
    }
}

extern "C" void kernel_launch(void* const* d_in, const int* in_sizes, int n_in,
                              void* d_out, int out_size, void* d_ws, size_t ws_size,
                              hipStream_t stream) {
    const float* in = (const float*)d_in[0];
    const float* wp = (const float*)d_in[1];
    const float* bp = (const float*)d_in[2];
    const float* dc = (const float*)d_in[3];
    const float* gm = (const float*)d_in[4];
    float* out = (float*)d_out;

    const size_t scan_bytes = (size_t)BATCH * CCH * HW * 4;    // 205.5 MB
    const size_t wcvt_bytes = (size_t)OCH * CCH * 2;           // 1 MB
    const size_t bin_bytes  = (size_t)BATCH * 16 * HW * 64;    // 102.8 MB

    int mode = 0;
    if (ws_size >= scan_bytes + wcvt_bytes + bin_bytes) mode = 2;
    else if (ws_size >= scan_bytes + wcvt_bytes)        mode = 1;

    unsigned char* wcvt = (unsigned char*)d_ws;
    unsigned char* bin  = (unsigned char*)d_ws + wcvt_bytes;
    float* scanp = (float*)((unsigned char*)d_ws +
        (mode == 2 ? wcvt_bytes + bin_bytes : mode == 1 ? wcvt_bytes : 0));

    dim3 g1(25, 2, BATCH);
    if (mode == 2) {
        preconv_w<<<64, 256, 0, stream>>>(wp, wcvt);
        conv_in<<<dim3(49, 16, BATCH), 256, 0, stream>>>(in, bin);
        gemm_bf16<2><<<g1, 512, 0, stream>>>(in, wp, wcvt, bin, bp, out, scanp);
    } else if (mode == 1) {
        preconv_w<<<64, 256, 0, stream>>>(wp, wcvt);
        gemm_bf16<1><<<g1, 512, 0, stream>>>(in, wp, wcvt, bin, bp, out, scanp);
    } else {
        gemm_bf16<0><<<g1, 512, 0, stream>>>(in, wp, wcvt, bin, bp, out, scanp);
    }

    scan_fuse<<<BATCH * CCH, 64, 0, stream>>>(in, scanp, dc, gm, out);
}

// Round 13
// 523.438 us; speedup vs baseline: 4.2188x; 1.0082x over previous
//
#include <hip/hip_runtime.h>
#include <cstddef>
#include <cstdint>

#define BATCH 32
#define CCH   512
#define OCH   1024
#define HW    3136
#define WDIM  56
#define NKT   16           // 512 / BK, BK=32

typedef __attribute__((ext_vector_type(8))) short short8v;  // 8 bf16
typedef __attribute__((ext_vector_type(4))) float f32x4;

// RNE round two fp32 to bf16, packed (x0 -> lo16, x1 -> hi16).
static __device__ __forceinline__ unsigned rne2(float x0, float x1) {
    unsigned u0 = __float_as_uint(x0), u1 = __float_as_uint(x1);
    u0 = u0 + 0x7fffu + ((u0 >> 16) & 1u);
    u1 = u1 + 0x7fffu + ((u1 >> 16) & 1u);
    return (u0 >> 16) | (u1 & 0xffff0000u);
}

// 4 slots of 16B per 64-B row; XOR swizzle (R10/R11-proven).
static __device__ __forceinline__ int physlot4(int s, int row) {
    return (s ^ (row & 3) ^ ((row >> 2) & 3)) & 3;
}

#define GLD_LDS16(gsrc, ldst) \
    __builtin_amdgcn_global_load_lds( \
        (const __attribute__((address_space(1))) void*)(gsrc), \
        (__attribute__((address_space(3))) void*)(ldst), 16, 0, 0)

#define MFMA16(a, bb, c) __builtin_amdgcn_mfma_f32_16x16x32_bf16((a), (bb), (c), 0, 0, 0)

// ---------------------------------------------------------------------------
// K0a: pre-convert weights (RNE bf16) into the LDS image (R10-proven):
// wcvt[o][kt] = 64 B: 4 slots of 8 bf16 k-octets, slot s at physlot4(s,o).
// ---------------------------------------------------------------------------
__global__ __launch_bounds__(256) void preconv_w(
    const float* __restrict__ wp, unsigned char* __restrict__ wcvt)
{
    const int id = blockIdx.x * 256 + threadIdx.x;   // 16384 = 1024 o x 16 kt
    const int o = id >> 4, kt = id & 15;
    const float* p = wp + (size_t)o * CCH + kt * 32;
    unsigned char* dst = wcvt + (size_t)o * 1024 + kt * 64;
    float4 v[8];
#pragma unroll
    for (int r = 0; r < 8; ++r) v[r] = *(const float4*)(p + 4 * r);
#pragma unroll
    for (int oc = 0; oc < 4; ++oc) {
        uint4 w;
        w.x = rne2(v[2*oc].x,   v[2*oc].y);
        w.y = rne2(v[2*oc].z,   v[2*oc].w);
        w.z = rne2(v[2*oc+1].x, v[2*oc+1].y);
        w.w = rne2(v[2*oc+1].z, v[2*oc+1].w);
        *(uint4*)(dst + physlot4(oc, o) * 16) = w;
    }
}

// ---------------------------------------------------------------------------
// K0b: convert+transpose input to bin[b][kt][n] 64-B chunks, PRE-SWIZZLED
// with physlot4(sub, n) (FIX vs R12: bin must be the byte-exact LDS image,
// since global_load_lds copies linearly and the frag read applies the
// swizzle — rule "both sides or neither").
// ---------------------------------------------------------------------------
__global__ __launch_bounds__(256) void conv_in(
    const float* __restrict__ in, unsigned char* __restrict__ bin)
{
    const int nt = blockIdx.x;      // 0..48 (64-n tiles)
    const int kt = blockIdx.y;      // 0..15
    const int b  = blockIdx.z;
    const int t  = threadIdx.x;
    __shared__ float sm[32 * 65];

    const int n0 = nt * 64;
    const int row = t >> 3;             // 0..31 (k within tile)
    const int c8  = (t & 7) * 8;        // 0..56
    const float* src = in + ((size_t)b * CCH + kt * 32 + row) * HW + n0 + c8;
    float4 v0 = *(const float4*)src;
    float4 v1 = *(const float4*)(src + 4);
    float* sr = sm + row * 65 + c8;
    sr[0] = v0.x; sr[1] = v0.y; sr[2] = v0.z; sr[3] = v0.w;
    sr[4] = v1.x; sr[5] = v1.y; sr[6] = v1.z; sr[7] = v1.w;
    __syncthreads();

    const int n = t >> 2, sub = t & 3;  // n 0..63, k-octet sub
    const int k0 = sub * 8;
    uint4 w;
    w.x = rne2(sm[(k0 + 0) * 65 + n], sm[(k0 + 1) * 65 + n]);
    w.y = rne2(sm[(k0 + 2) * 65 + n], sm[(k0 + 3) * 65 + n]);
    w.z = rne2(sm[(k0 + 4) * 65 + n], sm[(k0 + 5) * 65 + n]);
    w.w = rne2(sm[(k0 + 6) * 65 + n], sm[(k0 + 7) * 65 + n]);
    // physlot4 uses only row bits 0..3; local n shares them with global n.
    *(uint4*)(bin + (((size_t)b * 16 + kt) * HW + n0 + n) * 64 +
              physlot4(sub, n) * 16) = w;
}

// ---------------------------------------------------------------------------
// K1: m97-replica GEMM. Tile 128(o) x 128(n), BK=32, 256 threads = 4 waves
// (2x2 of 64x64, 4x4 frags). Both operands staged by pure global_load_lds
// (4 instrs/kt) from the byte-exact pre-swizzled images; zero in-kernel
// conversion. LDS 32 KB dbuf -> 4 blocks/CU: cross-block overlap hides the
// per-kt vmcnt(0) drain (m114/m97 mechanism). Grid ot-fastest -> XCD x owns
// o-tile x: 128 KB wcvt slice L2-pinned; bin (103 MB) L3-resident.
// ---------------------------------------------------------------------------
__global__ __launch_bounds__(256, 4) void gemm_m97(
    const unsigned char* __restrict__ wc,  // wcvt image
    const unsigned char* __restrict__ bin, // input image
    const float* __restrict__ bp,          // [1024]
    float* __restrict__ gate,              // d_out
    float* __restrict__ scan)              // ws scan region
{
    const int ot = blockIdx.x;   // 0..7  o-tile (fastest -> pins XCD)
    const int bx = blockIdx.y;   // 0..24 n-tile (last is half)
    const int b  = blockIdx.z;
    const int t  = threadIdx.x;
    const int lane = t & 63;
    const int wid  = t >> 6;           // 0..3
    const int wm = wid >> 1;           // o-strip of 64
    const int wn = wid & 1;            // n-strip of 64
    const int l15 = lane & 15, lko = lane >> 4;

    __shared__ __align__(16) unsigned char lds[32768];
    unsigned char* const A0 = lds;             // 8 KB (128 rows x 64 B)
    unsigned char* const A1 = lds + 8192;
    unsigned char* const B0 = lds + 16384;
    unsigned char* const B1 = lds + 24576;

    const int o0 = ot * 128;
    const int n0 = bx * 128;

    // staging sources (per-lane global, wave-uniform linear LDS dest)
    const unsigned char* aSrc = wc + (size_t)(o0 + (t >> 2)) * 1024 + (t & 3) * 16;
    const unsigned char* bSrc = bin + ((size_t)b * 16 * HW + n0) * 64 + t * 16;

    auto stage = [&](int kt, unsigned char* Ab, unsigned char* Bb) {
#pragma unroll
        for (int j = 0; j < 2; ++j)
            GLD_LDS16(aSrc + kt * 64 + (size_t)(j * 64) * 1024,
                      Ab + j * 4096 + wid * 1024);
#pragma unroll
        for (int j = 0; j < 2; ++j)
            GLD_LDS16(bSrc + (size_t)kt * (HW * 64) + j * 4096,
                      Bb + j * 4096 + wid * 1024);
    };

    f32x4 acc[4][4] = {};

    auto body = [&](int kt, unsigned char* Ac, unsigned char* Bc,
                    unsigned char* An, unsigned char* Bn) {
        // ---- stage next tile (DMA flies under the MFMAs) ----
        if (kt + 1 < NKT) stage(kt + 1, An, Bn);

        // ---- fragments ----
        short8v af[4], bf[4];
#pragma unroll
        for (int fi = 0; fi < 4; ++fi) {
            const int r = wm * 64 + fi * 16 + l15;
            af[fi] = *(const short8v*)(Ac + r * 64 + physlot4(lko, r) * 16);
        }
#pragma unroll
        for (int g = 0; g < 4; ++g) {
            const int n = wn * 64 + g * 16 + l15;
            bf[g] = *(const short8v*)(Bc + n * 64 + physlot4(lko, n) * 16);
        }

        __builtin_amdgcn_s_setprio(1);
#pragma unroll
        for (int fi = 0; fi < 4; ++fi)
#pragma unroll
            for (int g = 0; g < 4; ++g)
                acc[fi][g] = MFMA16(af[fi], bf[g], acc[fi][g]);
        __builtin_amdgcn_s_setprio(0);

        // ---- full drain + barrier (m97 structure; hidden by 4 blocks/CU) ----
        asm volatile("s_waitcnt vmcnt(0) lgkmcnt(0)" ::: "memory");
        __builtin_amdgcn_s_barrier();
        asm volatile("" ::: "memory");
    };

    // ---- prologue: tile 0 -> buf0 ----
    stage(0, A0, B0);
    asm volatile("s_waitcnt vmcnt(0)" ::: "memory");
    __builtin_amdgcn_s_barrier();
    asm volatile("" ::: "memory");

#pragma unroll 1
    for (int kt2 = 0; kt2 < NKT; kt2 += 2) {
        body(kt2,     A0, B0, A1, B1);
        body(kt2 + 1, A1, B1, A0, B0);
    }

    // ---- epilogue: bias + store (C: row = lko*4+rg, col = l15) ----
    float* dstb = (ot < 4) ? gate : scan;
    const int c0 = o0 & (CCH - 1);
#pragma unroll
    for (int f = 0; f < 4; ++f) {
        const int rowb = wm * 64 + f * 16 + lko * 4;
#pragma unroll
        for (int rg = 0; rg < 4; ++rg) {
            const float bias = bp[o0 + rowb + rg];
            float* drow = dstb + ((size_t)b * CCH + c0 + rowb + rg) * HW;
#pragma unroll
            for (int g = 0; g < 4; ++g) {
                const int n = n0 + wn * 64 + g * 16 + l15;
                if (n < HW) drow[n] = acc[f][g][rg] + bias;
            }
        }
    }
}

// ---------------------------------------------------------------------------
// Fallback GEMM (R0-proven fp32) if ws lacks room for bin.
// ---------------------------------------------------------------------------
__global__ __launch_bounds__(256) void gemm_proj(
    const float* __restrict__ in, const float* __restrict__ wp,
    const float* __restrict__ bp, float* __restrict__ gate,
    float* __restrict__ scan)
{
    const int bx = blockIdx.x, by = blockIdx.y, b = blockIdx.z;
    const int t = threadIdx.x;
    __shared__ float As[16][128];
    __shared__ float Bs[16][64];
    const float* Ab = wp + (size_t)(by * 128) * CCH;
    const float* Bb = in + (size_t)b * CCH * HW + bx * 64;
    float acc[8][4];
#pragma unroll
    for (int i = 0; i < 8; i++)
#pragma unroll
        for (int j = 0; j < 4; j++) acc[i][j] = 0.f;
    const int a_row = t >> 1, a_c = (t & 1) * 8;
    const int b_row = t >> 4, b_n = (t & 15) * 4;
    const int ty = t >> 4, tx = t & 15;
    for (int k0 = 0; k0 < CCH; k0 += 16) {
        float4 av0 = *(const float4*)(Ab + (size_t)a_row * CCH + k0 + a_c);
        float4 av1 = *(const float4*)(Ab + (size_t)a_row * CCH + k0 + a_c + 4);
        float4 bv  = *(const float4*)(Bb + (size_t)(k0 + b_row) * HW + b_n);
        __syncthreads();
        As[a_c + 0][a_row] = av0.x; As[a_c + 1][a_row] = av0.y;
        As[a_c + 2][a_row] = av0.z; As[a_c + 3][a_row] = av0.w;
        As[a_c + 4][a_row] = av1.x; As[a_c + 5][a_row] = av1.y;
        As[a_c + 6][a_row] = av1.z; As[a_c + 7][a_row] = av1.w;
        *(float4*)&Bs[b_row][b_n] = bv;
        __syncthreads();
#pragma unroll
        for (int kk = 0; kk < 16; kk++) {
            float4 a0 = *(const float4*)&As[kk][ty * 8];
            float4 a1 = *(const float4*)&As[kk][ty * 8 + 4];
            float4 bb = *(const float4*)&Bs[kk][tx * 4];
            float av[8] = {a0.x, a0.y, a0.z, a0.w, a1.x, a1.y, a1.z, a1.w};
            float bw[4] = {bb.x, bb.y, bb.z, bb.w};
#pragma unroll
            for (int i = 0; i < 8; i++)
#pragma unroll
                for (int j = 0; j < 4; j++)
                    acc[i][j] = fmaf(av[i], bw[j], acc[i][j]);
        }
    }
    const int n0 = bx * 64 + tx * 4;
#pragma unroll
    for (int i = 0; i < 8; i++) {
        const int o = by * 128 + ty * 8 + i;
        const float bias = bp[o];
        float4 v;
        v.x = acc[i][0] + bias; v.y = acc[i][1] + bias;
        v.z = acc[i][2] + bias; v.w = acc[i][3] + bias;
        float* dst;
        if (o < CCH) dst = gate + ((size_t)b * CCH + o) * HW + n0;
        else         dst = scan + ((size_t)b * CCH + (o - CCH)) * HW + n0;
        *(float4*)dst = v;
    }
}

// ---------------------------------------------------------------------------
// K2: per-(b,c) 2D discounted scan + fused epilogue (R0-proven).
// ---------------------------------------------------------------------------
__global__ __launch_bounds__(64) void scan_fuse(
    const float* __restrict__ in,
    const float* __restrict__ scanb,
    const float* __restrict__ disc,
    const float* __restrict__ gamma,
    float* gate_out)
{
    const int idx = blockIdx.x;
    const int c = idx & (CCH - 1);
    const size_t base = (size_t)idx * HW;
    const float d = disc[c];
    const float g = gamma[0];
    const int lane = threadIdx.x;

    __shared__ float L[WDIM * 57];

    if (lane < WDIM) {
        const int w = lane;
        float acc = 0.f;
#pragma unroll 4
        for (int h = 0; h < WDIM; h++) {
            acc = fmaf(d, acc, scanb[base + h * WDIM + w]);
            L[h * 57 + w] = acc;
        }
    }
    __syncthreads();
    if (lane < WDIM) {
        const int h = lane;
        float acc = 0.f;
#pragma unroll 4
        for (int w = 0; w < WDIM; w++) {
            acc = fmaf(d, acc, L[h * 57 + w]);
            L[h * 57 + w] = acc;
        }
    }
    __syncthreads();
    if (lane < WDIM) {
        const int w = lane;
#pragma unroll 4
        for (int h = 0; h < WDIM; h++) {
            const size_t off = base + h * WDIM + w;
            const float xc = L[h * 57 + w];
            const float sg = 1.f / (1.f + __expf(-xc));
            const float val = fmaf(g * gate_out[off], sg, in[off]);
            gate_out[off] = val;
        }
    }
}

extern "C" void kernel_launch(void* const* d_in, const int* in_sizes, int n_in,
                              void* d_out, int out_size, void* d_ws, size_t ws_size,
                              hipStream_t stream) {
    const float* in = (const float*)d_in[0];
    const float* wp = (const float*)d_in[1];
    const float* bp = (const float*)d_in[2];
    const float* dc = (const float*)d_in[3];
    const float* gm = (const float*)d_in[4];
    float* out = (float*)d_out;

    const size_t scan_bytes = (size_t)BATCH * CCH * HW * 4;    // 205.5 MB
    const size_t wcvt_bytes = (size_t)OCH * CCH * 2;           // 1 MB
    const size_t bin_bytes  = (size_t)BATCH * 16 * HW * 64;    // 102.8 MB
    const bool pre = ws_size >= scan_bytes + wcvt_bytes + bin_bytes;

    unsigned char* wcvt = (unsigned char*)d_ws;
    unsigned char* bin  = (unsigned char*)d_ws + wcvt_bytes;
    float* scanp = (float*)((unsigned char*)d_ws +
                            (pre ? wcvt_bytes + bin_bytes : 0));

    if (pre) {
        preconv_w<<<64, 256, 0, stream>>>(wp, wcvt);
        conv_in<<<dim3(49, 16, BATCH), 256, 0, stream>>>(in, bin);
        gemm_m97<<<dim3(8, 25, BATCH), 256, 0, stream>>>(wcvt, bin, bp, out, scanp);
    } else {
        gemm_proj<<<dim3(HW / 64, OCH / 128, BATCH), 256, 0, stream>>>(
            in, wp, bp, out, scanp);
    }

    scan_fuse<<<BATCH * CCH, 64, 0, stream>>>(in, scanp, dc, gm, out);
}